// Round 1
// 502.068 us; speedup vs baseline: 1.1060x; 1.1060x over previous
//
#include <hip/hip_runtime.h>

#define B 4
#define L 96
#define V 207
#define H 8
#define E 64
#define C 512            // H*E
#define LS (V*C)         // stride between consecutive l rows = 105984
#define TOPK 4
#define QPAD 68          // corr LDS row pitch (floats): 68%8=4 -> 2-way max on frag reads
#define TPAD 128         // agg LDS row pitch (floats), XOR-swizzled groups

// workspace layout (byte offsets)
#define MV_OFF 0                          // float mean_value[B*V*L]
#define IDX_OFF (B*V*L*4)                 // int   index[V*TOPK]
#define TC_OFF  (IDX_OFF + V*TOPK*4)      // float tmp_corr[B*V*TOPK]

typedef float f32x4 __attribute__((ext_vector_type(4)));
typedef _Float16 f16x8 __attribute__((ext_vector_type(8)));

// ---------------------------------------------------------------------------
// Kernel 1: per (b,v), mean over channels of circular cross-correlation,
// via MFMA on the 96x96 Gram matrix S[t1,t2] = sum_c Q[t1,c]*K[t2,c].
// fp32 inputs are split q = qh + ql (f16) and computed with 3 MFMAs
// (qh*kh + qh*kl + ql*kh); dropped ql*kl term is ~2^-22 relative.
// 4 waves in a 2x2 grid, each owning a 48x48 block = 3x3 tiles of 16x16.
// K-dim (channels) chunked by 64 through LDS (fp32, pad-68 rows).
// ---------------------------------------------------------------------------
__global__ __launch_bounds__(256) void corr_mean_kernel(
        const float* __restrict__ q, const float* __restrict__ k,
        float* __restrict__ mv) {
    __shared__ __attribute__((aligned(16))) float Qs[L * QPAD];
    __shared__ __attribute__((aligned(16))) float Ks[L * QPAD];
    __shared__ float corr[L];

    const int bid = blockIdx.x;
    const int b = bid / V;
    const int v = bid % V;
    const int tid = threadIdx.x;
    const int lane = tid & 63;
    const int wave = tid >> 6;
    const int lrow = lane & 15;          // row/col-within-tile for A/B frags
    const int lq = lane >> 4;            // k-quarter: k = lq*8 + [0,8)
    const int rbase = (wave >> 1) * 48;  // rows of S owned by this wave
    const int cbase = (wave & 1) * 48;   // cols of S owned by this wave

    const size_t base = ((size_t)b * L * V + v) * (size_t)C;

    f32x4 acc[3][3];
#pragma unroll
    for (int i = 0; i < 3; i++)
#pragma unroll
        for (int j = 0; j < 3; j++) acc[i][j] = (f32x4){0.f, 0.f, 0.f, 0.f};

    for (int c0 = 0; c0 < C; c0 += 64) {
        // Stage 96 rows x 64 channels of Q and K into LDS (fp32, float4).
#pragma unroll
        for (int it = 0; it < 6; it++) {
            const int id = tid + it * 256;       // 0..1535
            const int t = id >> 4;               // row 0..95
            const int s = id & 15;               // float4 slot 0..15
            const size_t g = base + (size_t)t * LS + c0 + s * 4;
            const float4 qv = *(const float4*)(q + g);
            const float4 kv = *(const float4*)(k + g);
            *(float4*)(Qs + t * QPAD + s * 4) = qv;
            *(float4*)(Ks + t * QPAD + s * 4) = kv;
        }
        __syncthreads();

#pragma unroll
        for (int kk = 0; kk < 2; kk++) {         // two K=32 steps per chunk
            const int soff = kk * 32 + lq * 8;   // float offset within row
            f16x8 qh[3], ql[3], kh[3], kl[3];
#pragma unroll
            for (int ti = 0; ti < 3; ti++) {
                const int t = rbase + ti * 16 + lrow;
                const float* p = Qs + t * QPAD + soff;
                const float4 a0 = *(const float4*)(p);
                const float4 a1 = *(const float4*)(p + 4);
                const float xs[8] = {a0.x, a0.y, a0.z, a0.w,
                                     a1.x, a1.y, a1.z, a1.w};
#pragma unroll
                for (int j = 0; j < 8; j++) {
                    const _Float16 h = (_Float16)xs[j];
                    qh[ti][j] = h;
                    ql[ti][j] = (_Float16)(xs[j] - (float)h);
                }
            }
#pragma unroll
            for (int tj = 0; tj < 3; tj++) {
                const int t = cbase + tj * 16 + lrow;
                const float* p = Ks + t * QPAD + soff;
                const float4 a0 = *(const float4*)(p);
                const float4 a1 = *(const float4*)(p + 4);
                const float xs[8] = {a0.x, a0.y, a0.z, a0.w,
                                     a1.x, a1.y, a1.z, a1.w};
#pragma unroll
                for (int j = 0; j < 8; j++) {
                    const _Float16 h = (_Float16)xs[j];
                    kh[tj][j] = h;
                    kl[tj][j] = (_Float16)(xs[j] - (float)h);
                }
            }
#pragma unroll
            for (int ti = 0; ti < 3; ti++)
#pragma unroll
                for (int tj = 0; tj < 3; tj++) {
                    acc[ti][tj] = __builtin_amdgcn_mfma_f32_16x16x32_f16(
                        qh[ti], kh[tj], acc[ti][tj], 0, 0, 0);
                    acc[ti][tj] = __builtin_amdgcn_mfma_f32_16x16x32_f16(
                        qh[ti], kl[tj], acc[ti][tj], 0, 0, 0);
                    acc[ti][tj] = __builtin_amdgcn_mfma_f32_16x16x32_f16(
                        ql[ti], kh[tj], acc[ti][tj], 0, 0, 0);
                }
        }
        __syncthreads();
    }

    if (tid < L) corr[tid] = 0.f;
    __syncthreads();

    // C/D layout (m89, dtype-independent): col = lane&15, row = lq*4 + reg.
    // acc[ti][tj] reg r holds S[t1][t2], t1 = rbase+16ti+lq*4+r,
    // t2 = cbase+16tj+lrow; contributes to tau = (t1 - t2) mod 96.
    // Pre-sum tiles with equal d = ti - tj (same tau per reg).
#pragma unroll
    for (int d = -2; d <= 2; d++) {
        f32x4 s = (f32x4){0.f, 0.f, 0.f, 0.f};
#pragma unroll
        for (int ti = 0; ti < 3; ti++) {
            const int tj = ti - d;
            if (tj >= 0 && tj < 3) s += acc[ti][tj];
        }
#pragma unroll
        for (int r = 0; r < 4; r++) {
            int tau = rbase - cbase + d * 16 + lq * 4 + r - lrow;
            tau = ((tau % L) + L) % L;
            atomicAdd(&corr[tau], s[r]);
        }
    }
    __syncthreads();

    if (tid < L) mv[((size_t)b * V + v) * L + tid] = corr[tid] * (1.0f / 512.0f);
}

// ---------------------------------------------------------------------------
// Kernel 2: per v — sum over b, wave-parallel top-4 (shfl butterfly,
// smaller-index tie-break), per-b softmax of gathered weights. 1 wave.
// ---------------------------------------------------------------------------
__global__ __launch_bounds__(64) void topk_softmax_kernel(
        const float* __restrict__ mv, int* __restrict__ idx,
        float* __restrict__ tc) {
    __shared__ float gm[L];
    __shared__ int sidx[TOPK];
    const int v = blockIdx.x;
    const int tid = threadIdx.x;   // 0..63

    {
        float s0 = 0.f, s1 = 0.f;
#pragma unroll
        for (int b = 0; b < B; b++) {
            s0 += mv[((size_t)b * V + v) * L + tid];
            if (tid < 32) s1 += mv[((size_t)b * V + v) * L + 64 + tid];
        }
        gm[tid] = s0;
        if (tid < 32) gm[64 + tid] = s1;
    }
    __syncthreads();

    for (int kk = 0; kk < TOPK; kk++) {
        float val = gm[tid];
        int id2 = tid;
        if (tid < 32) {
            const float v2 = gm[64 + tid];
            if (v2 > val) { val = v2; id2 = 64 + tid; }
        }
#pragma unroll
        for (int off = 32; off > 0; off >>= 1) {
            const float ov = __shfl_xor(val, off);
            const int oi = __shfl_xor(id2, off);
            if (ov > val || (ov == val && oi < id2)) { val = ov; id2 = oi; }
        }
        if (tid == 0) { sidx[kk] = id2; gm[id2] = -1e30f; }
        __syncthreads();
    }

    if (tid < B) {
        const int b = tid;
        float w[TOPK];
        float m = -1e30f;
#pragma unroll
        for (int kk = 0; kk < TOPK; kk++) {
            w[kk] = mv[((size_t)b * V + v) * L + sidx[kk]];
            m = fmaxf(m, w[kk]);
        }
        float s = 0.f;
#pragma unroll
        for (int kk = 0; kk < TOPK; kk++) { w[kk] = expf(w[kk] - m); s += w[kk]; }
        const float inv = 1.f / s;
#pragma unroll
        for (int kk = 0; kk < TOPK; kk++)
            tc[((size_t)b * V + v) * TOPK + kk] = w[kk] * inv;
    }
    if (tid < TOPK) idx[v * TOPK + tid] = sidx[tid];
}

// ---------------------------------------------------------------------------
// Kernel 3: out[b,l,v, e*8+h] = sum_kk w[b,v,kk] * values[b,(l+idx[v,kk])%L, v, h*64+e]
// One block per (b, v, e-quarter). LDS slab stored in output channel order,
// XOR-swizzled inside each 32-float group: slot (s^f4)*8 + h. This makes the
// 4 transposing scalar writes hit 32 distinct banks (was 8-way conflict) and
// keeps reads aligned float4 (conflict-free). Block index is XCD-chunked so
// the 4 quarters of one (b,v) share one XCD's L2 (they read complementary
// 64B halves of the same 128B lines).
// ---------------------------------------------------------------------------
__global__ __launch_bounds__(256) void agg_kernel(
        const float* __restrict__ val, const float* __restrict__ tc,
        const int* __restrict__ idx, float* __restrict__ out) {
    __shared__ __attribute__((aligned(16))) float T[L * TPAD];  // 48 KiB
    __shared__ int sidx[TOPK];
    __shared__ float sw[TOPK];

    const int p = blockIdx.x;
    const int bid = (p & 7) * ((B * V * 4) / 8) + (p >> 3);   // bijective: 3312 = 8*414
    const int qtr = bid & 3;              // e-quarter: e in [qtr*16, qtr*16+16)
    const int bv = bid >> 2;
    const int b = bv / V;
    const int v = bv % V;
    const int tid = threadIdx.x;
    const int e0 = qtr * 16;

    const size_t base = ((size_t)b * L * V + v) * (size_t)C;

    if (tid < TOPK) {
        sidx[tid] = idx[v * TOPK + tid];
        sw[tid] = tc[((size_t)b * V + v) * TOPK + tid];
    }

    // Stage with transpose: id in [0,3072): l = id>>5, h = (id&31)>>2, f4 = id&3.
    // Input float4 covers s=0..3 of channels h*64 + e0 + f4*4 + s;
    // store at group f4, swizzled slot (s^f4)*8 + h.
#pragma unroll
    for (int it = 0; it < 12; it++) {
        const int id = tid + it * 256;
        const int l = id >> 5;
        const int h = (id & 31) >> 2;
        const int f4 = id & 3;
        const float4 r = *(const float4*)(val + base + (size_t)l * LS + h * 64 + e0 + f4 * 4);
        float* dst = T + l * TPAD + f4 * 32 + h;
        dst[(0 ^ f4) * 8] = r.x;
        dst[(1 ^ f4) * 8] = r.y;
        dst[(2 ^ f4) * 8] = r.z;
        dst[(3 ^ f4) * 8] = r.w;
    }
    __syncthreads();

    const float w0 = sw[0], w1 = sw[1], w2 = sw[2], w3 = sw[3];
    const int i0 = sidx[0], i1 = sidx[1], i2 = sidx[2], i3 = sidx[3];

    // Output: id in [0,3072): l = id>>5, m = id&31 -> output float4 at
    // channel qtr*128 + 4m (coalesced). Read slab with inverse swizzle.
#pragma unroll
    for (int it = 0; it < 12; it++) {
        const int id = tid + it * 256;
        const int l = id >> 5;
        const int m = id & 31;
        const int f4 = m >> 3;
        const int w = m & 7;
        const int off = f4 * 32 + (((((w >> 1) ^ f4) << 1) | (w & 1)) << 2);
        int l0 = l + i0; if (l0 >= L) l0 -= L;
        int l1 = l + i1; if (l1 >= L) l1 -= L;
        int l2 = l + i2; if (l2 >= L) l2 -= L;
        int l3 = l + i3; if (l3 >= L) l3 -= L;
        const float4 r0 = *(const float4*)(T + l0 * TPAD + off);
        const float4 r1 = *(const float4*)(T + l1 * TPAD + off);
        const float4 r2 = *(const float4*)(T + l2 * TPAD + off);
        const float4 r3 = *(const float4*)(T + l3 * TPAD + off);
        float4 o;
        o.x = w0 * r0.x + w1 * r1.x + w2 * r2.x + w3 * r3.x;
        o.y = w0 * r0.y + w1 * r1.y + w2 * r2.y + w3 * r3.y;
        o.z = w0 * r0.z + w1 * r1.z + w2 * r2.z + w3 * r3.z;
        o.w = w0 * r0.w + w1 * r1.w + w2 * r2.w + w3 * r3.w;
        *(float4*)(out + base + (size_t)l * LS + qtr * 128 + m * 4) = o;
    }
}

extern "C" void kernel_launch(void* const* d_in, const int* in_sizes, int n_in,
                              void* d_out, int out_size, void* d_ws, size_t ws_size,
                              hipStream_t stream) {
    const float* q = (const float*)d_in[0];
    const float* k = (const float*)d_in[1];
    const float* val = (const float*)d_in[2];
    float* out = (float*)d_out;
    char* ws = (char*)d_ws;
    float* mv = (float*)(ws + MV_OFF);
    int* idx = (int*)(ws + IDX_OFF);
    float* tc = (float*)(ws + TC_OFF);

    corr_mean_kernel<<<B * V, 256, 0, stream>>>(q, k, mv);
    topk_softmax_kernel<<<V, 64, 0, stream>>>(mv, idx, tc);
    agg_kernel<<<B * V * 4, 256, 0, stream>>>(val, tc, idx, out);
}